// Round 6
// baseline (340.544 us; speedup 1.0000x reference)
//
#include <hip/hip_runtime.h>
#include <hip/hip_cooperative_groups.h>
#include <math.h>

#pragma clang fp contract(off)

namespace cg = cooperative_groups;

constexpr int NB  = 16;    // batch
constexpr int NR  = 4096;  // rois per image
constexpr int NC  = 81;    // classes (incl. background)
constexpr int KK  = 200;   // per-class candidate cap == max_total
constexpr int CAP = 4096;  // max kept entries per image
constexpr int SEGCAP = 1024;              // fixed-stride per-(b,c) candidate segment
constexpr int ROWS_PER_BLK = 64;
constexpr int GRID = NB * NR / ROWS_PER_BLK;  // 1024 blocks
constexpr int TCHUNK = 256;               // entries ranked per block in topk phase
constexpr int NCHUNK = CAP / TCHUNK;      // 16 blocks per image
constexpr int OUT_ELEMS = NB * KK * 6;    // boxes(4) + labels(1) + scores(1)
constexpr float SCORE_TH = 0.5f;
constexpr float IOU_TH   = 0.5f;
constexpr float EPSF     = 1e-8f;

struct Entry {            // 32 bytes
    float s;
    int   cls;
    int   aux;            // roi index (cand) or pre-NMS rank k (final)
    int   pad;
    float y1, x1, y2, x2;
};
static_assert(sizeof(Entry) == 32, "Entry must be 32B");

struct SK { float s; int key; };   // 8B packed (score, cls*KK + prenms_rank)

union SMem {
    float stage[ROWS_PER_BLK * NC];                 // classify: 20736 B
    struct {                                        // perclass: 30180 B
        float ls[SEGCAP], ly1[SEGCAP], lx1[SEGCAP], ly2[SEGCAP], lx2[SEGCAP];
        int   lroi[SEGCAP];
        float ss[KK], sy1[KK], sx1[KK], sy2[KK], sx2[KK], sar[KK];
        int   skeep[KK];
        int   sbase;
    } pc;
    struct { float sS[CAP]; int sKy[CAP]; } tk;     // topk: 32768 B
};

__device__ __forceinline__ void decode_box(const float4& a, const float4& d,
                                           float& y1, float& x1, float& y2, float& x2) {
    float ah  = a.z - a.x;
    float aw  = a.w - a.y;
    float acy = a.x + 0.5f * ah;
    float acx = a.y + 0.5f * aw;
    float dy = d.x * 0.1f, dx = d.y * 0.1f;
    float dh = d.z * 0.2f, dw = d.w * 0.2f;
    float bh  = expf(dh) * ah;
    float bw  = expf(dw) * aw;
    float bcy = dy * ah + acy;
    float bcx = dx * aw + acx;
    y1 = bcy - 0.5f * bh;
    x1 = bcx - 0.5f * bw;
    y2 = y1 + bh;
    x2 = x1 + bw;
}

// ---------------- fused cooperative kernel ----------------
__global__ __launch_bounds__(256, 4)
void k_fused(const float* __restrict__ roi, const float* __restrict__ deltas,
             const float* __restrict__ probs, int* __restrict__ counts,
             int* __restrict__ final_count, Entry* __restrict__ cand,
             Entry* __restrict__ fin, SK* __restrict__ sk,
             float* __restrict__ out) {
    cg::grid_group grid = cg::this_grid();
    __shared__ SMem sm;
    const int tid = threadIdx.x;
    const int bid = blockIdx.x;
    const int gtid = bid * 256 + tid;

    // ---- phase 0: zero counters and output ----
    if (gtid < NB * NC) counts[gtid] = 0;
    if (gtid < NB) final_count[gtid] = 0;
    for (int j = gtid; j < OUT_ELEMS; j += GRID * 256) out[j] = 0.f;
    grid.sync();

    // ---- phase 1: classify (block bid handles 64 rows) ----
    {
        const float4* src = (const float4*)(probs + (size_t)bid * ROWS_PER_BLK * NC);
        float4* dst = (float4*)sm.stage;
        for (int v = tid; v < ROWS_PER_BLK * NC / 4; v += 256) dst[v] = src[v];
        __syncthreads();

        int g = tid >> 2;            // row within block
        int j = tid & 3;             // sub-lane within row group
        const float* row = sm.stage + g * NC;
        float m = -1.0f;
        int am = 127;
        for (int c = j; c < NC; c += 4) {
            float v = row[c];
            if (v > m) { m = v; am = c; }          // first-max within subset
        }
        for (int mask = 1; mask <= 2; mask <<= 1) {  // tie -> smaller index
            float om = __shfl_xor(m, mask);
            int   oi = __shfl_xor(am, mask);
            if (om > m || (om == m && oi < am)) { m = om; am = oi; }
        }
        if (j == 0 && am != 0 && m > SCORE_TH) {
            int r = bid * ROWS_PER_BLK + g;
            int b = r / NR;
            float4 a = ((const float4*)roi)[r];
            float4 d = *(const float4*)(deltas + ((size_t)r * NC + am) * 4);
            float y1, x1, y2, x2;
            decode_box(a, d, y1, x1, y2, x2);
            int slot = atomicAdd(&counts[b * NC + am], 1);
            if (slot < SEGCAP) {
                Entry* e = &cand[(size_t)(b * NC + am) * SEGCAP + slot];
                e->s = m; e->cls = am; e->aux = r % NR; e->pad = 0;
                e->y1 = y1; e->x1 = x1; e->y2 = y2; e->x2 = x2;
            }
        }
    }
    grid.sync();

    // ---- phase 2: per-(image,class) rank -> NMS -> append ----
    for (int seg = bid; seg < NB * NC; seg += GRID) {
        int b = seg / NC;
        int c = seg % NC;
        if (c == 0) continue;                 // uniform per block
        int Mc = counts[seg];
        if (Mc > SEGCAP) Mc = SEGCAP;
        if (Mc == 0) continue;                // uniform per block
        __syncthreads();                      // protect LDS reuse across segs

        const Entry* segp = cand + (size_t)seg * SEGCAP;
        for (int i = tid; i < Mc; i += 256) {
            Entry e = segp[i];
            sm.pc.ls[i] = e.s; sm.pc.lroi[i] = e.aux;
            sm.pc.ly1[i] = e.y1; sm.pc.lx1[i] = e.x1;
            sm.pc.ly2[i] = e.y2; sm.pc.lx2[i] = e.x2;
        }
        __syncthreads();

        // stable rank by (score desc, roi asc) — lax.top_k order
        for (int i = tid; i < Mc; i += 256) {
            float si = sm.pc.ls[i]; int ri = sm.pc.lroi[i];
            int rank = 0;
            for (int j = 0; j < Mc; ++j) {
                float sj = sm.pc.ls[j]; int rj = sm.pc.lroi[j];
                rank += (int)((sj > si) | ((sj == si) & (rj < ri)));
            }
            if (rank < KK) {
                sm.pc.ss[rank] = si;
                sm.pc.sy1[rank] = sm.pc.ly1[i]; sm.pc.sx1[rank] = sm.pc.lx1[i];
                sm.pc.sy2[rank] = sm.pc.ly2[i]; sm.pc.sx2[rank] = sm.pc.lx2[i];
                sm.pc.sar[rank] = fmaxf(sm.pc.ly2[i] - sm.pc.ly1[i], 0.f) *
                                  fmaxf(sm.pc.lx2[i] - sm.pc.lx1[i], 0.f);
            }
        }
        __syncthreads();

        int L = Mc < KK ? Mc : KK;
        for (int i = tid; i < L; i += 256) sm.pc.skeep[i] = 1;
        __syncthreads();

        // greedy NMS: sequential over i, parallel over j (reference scan semantics)
        for (int i = 0; i < L; ++i) {
            if (sm.pc.skeep[i]) {
                float yi1 = sm.pc.sy1[i], xi1 = sm.pc.sx1[i];
                float yi2 = sm.pc.sy2[i], xi2 = sm.pc.sx2[i], ai = sm.pc.sar[i];
                for (int j = i + 1 + tid; j < L; j += 256) {
                    if (!sm.pc.skeep[j]) continue;
                    float yy1 = fmaxf(yi1, sm.pc.sy1[j]), xx1 = fmaxf(xi1, sm.pc.sx1[j]);
                    float yy2 = fminf(yi2, sm.pc.sy2[j]), xx2 = fminf(xi2, sm.pc.sx2[j]);
                    float inter = fmaxf(yy2 - yy1, 0.f) * fmaxf(xx2 - xx1, 0.f);
                    float uni = ai + sm.pc.sar[j] - inter;
                    if (inter / (uni + EPSF) > IOU_TH) sm.pc.skeep[j] = 0;
                }
            }
            __syncthreads();
        }

        // one atomic per block, parallel prefix compaction
        if (tid == 0) {
            int tot = 0;
            for (int i = 0; i < L; ++i) tot += sm.pc.skeep[i];
            sm.pc.sbase = atomicAdd(&final_count[b], tot);
        }
        __syncthreads();
        int base = sm.pc.sbase;

        for (int i = tid; i < L; i += 256) {
            if (sm.pc.skeep[i]) {
                int pos = 0;
                for (int j = 0; j < i; ++j) pos += sm.pc.skeep[j];
                int slot = base + pos;
                if (slot < CAP) {
                    Entry* fo = &fin[(size_t)b * CAP + slot];
                    fo->s = sm.pc.ss[i]; fo->cls = c; fo->aux = i; fo->pad = 0;
                    fo->y1 = sm.pc.sy1[i]; fo->x1 = sm.pc.sx1[i];
                    fo->y2 = sm.pc.sy2[i]; fo->x2 = sm.pc.sx2[i];
                    sk[(size_t)b * CAP + slot].s = sm.pc.ss[i];
                    sk[(size_t)b * CAP + slot].key = c * KK + i;
                }
            }
        }
        __syncthreads();   // all reads of sm.pc done before next seg overwrites
    }
    grid.sync();

    // ---- phase 3: image-level stable top-200 ----
    if (bid < NB * NCHUNK) {
        int b     = bid / NCHUNK;
        int chunk = bid % NCHUNK;
        int M = final_count[b];
        if (M > CAP) M = CAP;
        if (chunk * TCHUNK < M) {
            const SK* list = sk + (size_t)b * CAP;
            for (int i = tid; i < M; i += 256) {
                SK v = list[i];
                sm.tk.sS[i] = v.s; sm.tk.sKy[i] = v.key;
            }
            __syncthreads();
            int e = chunk * TCHUNK + tid;
            if (e < M) {
                float se = sm.tk.sS[e]; int ke = sm.tk.sKy[e];
                int rank = 0;
                for (int j = 0; j < M; ++j) {
                    float sj = sm.tk.sS[j]; int kj = sm.tk.sKy[j];
                    rank += (int)((sj > se) | ((sj == se) & (kj < ke)));
                }
                if (rank < KK) {
                    Entry en = fin[(size_t)b * CAP + e];
                    float* obox = out + (size_t)b * KK * 4;
                    float* olbl = out + (size_t)NB * KK * 4 + (size_t)b * KK;
                    float* osc  = out + (size_t)NB * KK * 5 + (size_t)b * KK;
                    obox[rank * 4 + 0] = fminf(fmaxf(en.y1, 0.f), 1.f);
                    obox[rank * 4 + 1] = fminf(fmaxf(en.x1, 0.f), 1.f);
                    obox[rank * 4 + 2] = fminf(fmaxf(en.y2, 0.f), 1.f);
                    obox[rank * 4 + 3] = fminf(fmaxf(en.x2, 0.f), 1.f);
                    olbl[rank] = (float)en.cls;
                    osc[rank]  = en.s;
                }
            }
        }
    }
}

// ---------------- fallback path (proven 4-kernel pipeline) ----------------
__global__ void k_init(int* __restrict__ counts, int* __restrict__ final_count,
                       float* __restrict__ out) {
    int i = blockIdx.x * blockDim.x + threadIdx.x;
    if (i < NB * NC) counts[i] = 0;
    if (i < NB) final_count[i] = 0;
    for (int j = i; j < OUT_ELEMS; j += gridDim.x * blockDim.x) out[j] = 0.f;
}

__global__ void k_classify(const float* __restrict__ roi,
                           const float* __restrict__ deltas,
                           const float* __restrict__ probs,
                           int* __restrict__ counts,
                           Entry* __restrict__ cand) {
    __shared__ float lp[ROWS_PER_BLK * NC];
    const float4* src = (const float4*)(probs + (size_t)blockIdx.x * ROWS_PER_BLK * NC);
    float4* dst = (float4*)lp;
    for (int v = threadIdx.x; v < ROWS_PER_BLK * NC / 4; v += blockDim.x) dst[v] = src[v];
    __syncthreads();
    int g = threadIdx.x >> 2, j = threadIdx.x & 3;
    const float* row = lp + g * NC;
    float m = -1.0f; int am = 127;
    for (int c = j; c < NC; c += 4) { float v = row[c]; if (v > m) { m = v; am = c; } }
    for (int mask = 1; mask <= 2; mask <<= 1) {
        float om = __shfl_xor(m, mask); int oi = __shfl_xor(am, mask);
        if (om > m || (om == m && oi < am)) { m = om; am = oi; }
    }
    if (j != 0) return;
    if (am == 0 || !(m > SCORE_TH)) return;
    int r = blockIdx.x * ROWS_PER_BLK + g;
    int b = r / NR;
    float4 a = ((const float4*)roi)[r];
    float4 d = *(const float4*)(deltas + ((size_t)r * NC + am) * 4);
    float y1, x1, y2, x2;
    decode_box(a, d, y1, x1, y2, x2);
    int slot = atomicAdd(&counts[b * NC + am], 1);
    if (slot < SEGCAP) {
        Entry* e = &cand[(size_t)(b * NC + am) * SEGCAP + slot];
        e->s = m; e->cls = am; e->aux = r % NR; e->pad = 0;
        e->y1 = y1; e->x1 = x1; e->y2 = y2; e->x2 = x2;
    }
}

__global__ void k_perclass(const int* __restrict__ counts,
                           const Entry* __restrict__ cand,
                           int* __restrict__ final_count,
                           Entry* __restrict__ fin,
                           SK* __restrict__ sk) {
    int b = blockIdx.x / NC, c = blockIdx.x % NC;
    if (c == 0) return;
    int Mc = counts[b * NC + c];
    if (Mc > SEGCAP) Mc = SEGCAP;
    if (Mc == 0) return;
    const Entry* seg = cand + (size_t)(b * NC + c) * SEGCAP;
    __shared__ SMem sm;
    for (int i = threadIdx.x; i < Mc; i += blockDim.x) {
        Entry e = seg[i];
        sm.pc.ls[i] = e.s; sm.pc.lroi[i] = e.aux;
        sm.pc.ly1[i] = e.y1; sm.pc.lx1[i] = e.x1; sm.pc.ly2[i] = e.y2; sm.pc.lx2[i] = e.x2;
    }
    __syncthreads();
    for (int i = threadIdx.x; i < Mc; i += blockDim.x) {
        float si = sm.pc.ls[i]; int ri = sm.pc.lroi[i];
        int rank = 0;
        for (int j = 0; j < Mc; ++j) {
            float sj = sm.pc.ls[j]; int rj = sm.pc.lroi[j];
            rank += (int)((sj > si) | ((sj == si) & (rj < ri)));
        }
        if (rank < KK) {
            sm.pc.ss[rank] = si;
            sm.pc.sy1[rank] = sm.pc.ly1[i]; sm.pc.sx1[rank] = sm.pc.lx1[i];
            sm.pc.sy2[rank] = sm.pc.ly2[i]; sm.pc.sx2[rank] = sm.pc.lx2[i];
            sm.pc.sar[rank] = fmaxf(sm.pc.ly2[i] - sm.pc.ly1[i], 0.f) *
                              fmaxf(sm.pc.lx2[i] - sm.pc.lx1[i], 0.f);
        }
    }
    __syncthreads();
    int L = Mc < KK ? Mc : KK;
    for (int i = threadIdx.x; i < L; i += blockDim.x) sm.pc.skeep[i] = 1;
    __syncthreads();
    for (int i = 0; i < L; ++i) {
        if (sm.pc.skeep[i]) {
            float yi1 = sm.pc.sy1[i], xi1 = sm.pc.sx1[i];
            float yi2 = sm.pc.sy2[i], xi2 = sm.pc.sx2[i], ai = sm.pc.sar[i];
            for (int j = i + 1 + threadIdx.x; j < L; j += blockDim.x) {
                if (!sm.pc.skeep[j]) continue;
                float yy1 = fmaxf(yi1, sm.pc.sy1[j]), xx1 = fmaxf(xi1, sm.pc.sx1[j]);
                float yy2 = fminf(yi2, sm.pc.sy2[j]), xx2 = fminf(xi2, sm.pc.sx2[j]);
                float inter = fmaxf(yy2 - yy1, 0.f) * fmaxf(xx2 - xx1, 0.f);
                float uni = ai + sm.pc.sar[j] - inter;
                if (inter / (uni + EPSF) > IOU_TH) sm.pc.skeep[j] = 0;
            }
        }
        __syncthreads();
    }
    if (threadIdx.x == 0) {
        int tot = 0;
        for (int i = 0; i < L; ++i) tot += sm.pc.skeep[i];
        sm.pc.sbase = atomicAdd(&final_count[b], tot);
    }
    __syncthreads();
    int base = sm.pc.sbase;
    for (int i = threadIdx.x; i < L; i += blockDim.x) {
        if (sm.pc.skeep[i]) {
            int pos = 0;
            for (int j = 0; j < i; ++j) pos += sm.pc.skeep[j];
            int slot = base + pos;
            if (slot < CAP) {
                Entry* fo = &fin[(size_t)b * CAP + slot];
                fo->s = sm.pc.ss[i]; fo->cls = c; fo->aux = i; fo->pad = 0;
                fo->y1 = sm.pc.sy1[i]; fo->x1 = sm.pc.sx1[i];
                fo->y2 = sm.pc.sy2[i]; fo->x2 = sm.pc.sx2[i];
                sk[(size_t)b * CAP + slot].s = sm.pc.ss[i];
                sk[(size_t)b * CAP + slot].key = c * KK + i;
            }
        }
    }
}

__global__ void k_topk(const int* __restrict__ final_count,
                       const Entry* __restrict__ fin,
                       const SK* __restrict__ sk,
                       float* __restrict__ out) {
    int b = blockIdx.x / NCHUNK, chunk = blockIdx.x % NCHUNK;
    int M = final_count[b];
    if (M > CAP) M = CAP;
    if (chunk * TCHUNK >= M) return;
    __shared__ SMem sm;
    const SK* list = sk + (size_t)b * CAP;
    for (int i = threadIdx.x; i < M; i += blockDim.x) {
        SK v = list[i];
        sm.tk.sS[i] = v.s; sm.tk.sKy[i] = v.key;
    }
    __syncthreads();
    int e = chunk * TCHUNK + threadIdx.x;
    if (e >= M) return;
    float se = sm.tk.sS[e]; int ke = sm.tk.sKy[e];
    int rank = 0;
    for (int j = 0; j < M; ++j) {
        float sj = sm.tk.sS[j]; int kj = sm.tk.sKy[j];
        rank += (int)((sj > se) | ((sj == se) & (kj < ke)));
    }
    if (rank < KK) {
        Entry en = fin[(size_t)b * CAP + e];
        float* obox = out + (size_t)b * KK * 4;
        float* olbl = out + (size_t)NB * KK * 4 + (size_t)b * KK;
        float* osc  = out + (size_t)NB * KK * 5 + (size_t)b * KK;
        obox[rank * 4 + 0] = fminf(fmaxf(en.y1, 0.f), 1.f);
        obox[rank * 4 + 1] = fminf(fmaxf(en.x1, 0.f), 1.f);
        obox[rank * 4 + 2] = fminf(fmaxf(en.y2, 0.f), 1.f);
        obox[rank * 4 + 3] = fminf(fmaxf(en.x2, 0.f), 1.f);
        olbl[rank] = (float)en.cls;
        osc[rank]  = en.s;
    }
}

extern "C" void kernel_launch(void* const* d_in, const int* in_sizes, int n_in,
                              void* d_out, int out_size, void* d_ws, size_t ws_size,
                              hipStream_t stream) {
    const float* roi    = (const float*)d_in[0];
    const float* deltas = (const float*)d_in[1];
    const float* probs  = (const float*)d_in[2];
    float* out = (float*)d_out;

    int* ws_i        = (int*)d_ws;
    int* counts      = ws_i;                 // NB*NC
    int* final_count = ws_i + NB * NC;       // NB
    Entry* cand = (Entry*)((char*)d_ws + 16384);              // NB*NC*SEGCAP*32B = 42.5MB
    Entry* fin  = cand + (size_t)NB * NC * SEGCAP;            // 2MB
    SK*    sk   = (SK*)(fin + (size_t)NB * CAP);              // 512KB

    void* args[] = { (void*)&roi, (void*)&deltas, (void*)&probs, (void*)&counts,
                     (void*)&final_count, (void*)&cand, (void*)&fin, (void*)&sk,
                     (void*)&out };
    hipError_t err = hipLaunchCooperativeKernel((const void*)k_fused,
                                                dim3(GRID), dim3(256),
                                                args, 0, stream);
    if (err != hipSuccess) {
        // fallback: proven 4-kernel pipeline
        k_init<<<80, 256, 0, stream>>>(counts, final_count, out);
        k_classify<<<GRID, 256, 0, stream>>>(roi, deltas, probs, counts, cand);
        k_perclass<<<NB * NC, 256, 0, stream>>>(counts, cand, final_count, fin, sk);
        k_topk<<<NB * NCHUNK, 256, 0, stream>>>(final_count, fin, sk, out);
    }
}

// Round 7
// 91.208 us; speedup vs baseline: 3.7337x; 3.7337x over previous
//
#include <hip/hip_runtime.h>
#include <math.h>

#pragma clang fp contract(off)

constexpr int NB  = 16;    // batch
constexpr int NR  = 4096;  // rois per image
constexpr int NC  = 81;    // classes (incl. background)
constexpr int KK  = 200;   // per-class candidate cap == max_total
constexpr int CAP = 4096;  // max kept entries per image
constexpr int SEGCAP = 1024;              // fixed-stride per-(b,c) candidate segment
constexpr int ROWS_PER_BLK = 64;
constexpr int GRID = NB * NR / ROWS_PER_BLK;  // 1024 blocks
constexpr int TCHUNK = 256;               // entries ranked per block in topk
constexpr int NCHUNK = CAP / TCHUNK;      // 16 blocks per image
constexpr float SCORE_TH = 0.5f;
constexpr float IOU_TH   = 0.5f;
constexpr float EPSF     = 1e-8f;

struct Entry {            // 32 bytes
    float s;
    int   cls;
    int   aux;            // roi index (cand) or pre-NMS rank k (final)
    int   pad;
    float y1, x1, y2, x2;
};
static_assert(sizeof(Entry) == 32, "Entry must be 32B");

struct SK { float s; int key; };   // 8B packed (score, cls*KK + prenms_rank)

__device__ __forceinline__ void decode_box(const float4& a, const float4& d,
                                           float& y1, float& x1, float& y2, float& x2) {
    float ah  = a.z - a.x;
    float aw  = a.w - a.y;
    float acy = a.x + 0.5f * ah;
    float acx = a.y + 0.5f * aw;
    float dy = d.x * 0.1f, dx = d.y * 0.1f;
    float dh = d.z * 0.2f, dw = d.w * 0.2f;
    float bh  = expf(dh) * ah;
    float bw  = expf(dw) * aw;
    float bcy = dy * ah + acy;
    float bcx = dx * aw + acx;
    y1 = bcy - 0.5f * bh;
    x1 = bcx - 0.5f * bw;
    y2 = y1 + bh;
    x2 = x1 + bw;
}

// 4 threads per ROI: LDS-staged coalesced probs, shfl argmax (first-max rule),
// leader decodes box and scatters into fixed-stride (b,c) segment.
__global__ void k_classify(const float* __restrict__ roi,
                           const float* __restrict__ deltas,
                           const float* __restrict__ probs,
                           int* __restrict__ counts,
                           Entry* __restrict__ cand) {
    __shared__ float lp[ROWS_PER_BLK * NC];   // 20736 B
    const float4* src = (const float4*)(probs + (size_t)blockIdx.x * ROWS_PER_BLK * NC);
    float4* dst = (float4*)lp;
    for (int v = threadIdx.x; v < ROWS_PER_BLK * NC / 4; v += blockDim.x) dst[v] = src[v];
    __syncthreads();

    int g = threadIdx.x >> 2;       // row within block
    int j = threadIdx.x & 3;        // sub-lane within row group
    const float* row = lp + g * NC;
    float m = -1.0f;
    int am = 127;
    for (int c = j; c < NC; c += 4) {
        float v = row[c];
        if (v > m) { m = v; am = c; }            // first-max within subset
    }
    for (int mask = 1; mask <= 2; mask <<= 1) {  // tie -> smaller index (jnp.argmax)
        float om = __shfl_xor(m, mask);
        int   oi = __shfl_xor(am, mask);
        if (om > m || (om == m && oi < am)) { m = om; am = oi; }
    }
    if (j != 0) return;
    if (am == 0 || !(m > SCORE_TH)) return;      // background or below threshold

    int r = blockIdx.x * ROWS_PER_BLK + g;
    int b = r / NR;
    float4 a = ((const float4*)roi)[r];
    float4 d = *(const float4*)(deltas + ((size_t)r * NC + am) * 4);
    float y1, x1, y2, x2;
    decode_box(a, d, y1, x1, y2, x2);
    int slot = atomicAdd(&counts[b * NC + am], 1);
    if (slot < SEGCAP) {
        Entry* e = &cand[(size_t)(b * NC + am) * SEGCAP + slot];
        e->s = m; e->cls = am; e->aux = r % NR; e->pad = 0;
        e->y1 = y1; e->x1 = x1; e->y2 = y2; e->x2 = x2;
    }
}

// One block per (image,class): LDS rank -> top-200 -> wave-synchronous greedy NMS
// (wave 0, no barriers in the i-loop) -> aggregated append.
__global__ void k_perclass(const int* __restrict__ counts,
                           const Entry* __restrict__ cand,
                           int* __restrict__ final_count,
                           Entry* __restrict__ fin,
                           SK* __restrict__ sk) {
    int b = blockIdx.x / NC, c = blockIdx.x % NC;
    if (c == 0) return;
    int Mc = counts[b * NC + c];
    if (Mc > SEGCAP) Mc = SEGCAP;
    if (Mc == 0) return;
    const Entry* seg = cand + (size_t)(b * NC + c) * SEGCAP;

    __shared__ float ls[SEGCAP], ly1[SEGCAP], lx1[SEGCAP], ly2[SEGCAP], lx2[SEGCAP];
    __shared__ int   lroi[SEGCAP];
    __shared__ float ss[KK], sy1[KK], sx1[KK], sy2[KK], sx2[KK], sar[KK];
    __shared__ int   skeep[KK];
    __shared__ int   sbase;

    for (int i = threadIdx.x; i < Mc; i += blockDim.x) {
        Entry e = seg[i];
        ls[i] = e.s; lroi[i] = e.aux;
        ly1[i] = e.y1; lx1[i] = e.x1; ly2[i] = e.y2; lx2[i] = e.x2;
    }
    __syncthreads();

    // stable rank by (score desc, roi asc) — lax.top_k order
    for (int i = threadIdx.x; i < Mc; i += blockDim.x) {
        float si = ls[i]; int ri = lroi[i];
        int rank = 0;
        for (int j = 0; j < Mc; ++j) {
            float sj = ls[j]; int rj = lroi[j];
            rank += (int)((sj > si) | ((sj == si) & (rj < ri)));
        }
        if (rank < KK) {
            ss[rank] = si;
            sy1[rank] = ly1[i]; sx1[rank] = lx1[i];
            sy2[rank] = ly2[i]; sx2[rank] = lx2[i];
            sar[rank] = fmaxf(ly2[i] - ly1[i], 0.f) * fmaxf(lx2[i] - lx1[i], 0.f);
        }
    }
    __syncthreads();

    int L = Mc < KK ? Mc : KK;

    // ---- wave-synchronous greedy NMS on wave 0 (items j owned by lane j&63,
    //      slot j>>6; keep bits in a per-lane register mask; no barriers) ----
    if (threadIdx.x < 64) {
        int lane = threadIdx.x;
        float by1[4], bx1[4], by2[4], bx2[4], bar[4];
        #pragma unroll
        for (int s = 0; s < 4; ++s) {
            int jj = s * 64 + lane;
            if (jj < L) { by1[s] = sy1[jj]; bx1[s] = sx1[jj]; by2[s] = sy2[jj];
                          bx2[s] = sx2[jj]; bar[s] = sar[jj]; }
        }
        int kmask = 0;
        #pragma unroll
        for (int s = 0; s < 4; ++s) if (s * 64 + lane < L) kmask |= 1 << s;

        for (int i = 0; i < L; ++i) {
            int oi = i & 63, si = i >> 6;                 // owner lane, slot (uniform si)
            int keep_i = (__shfl(kmask, oi) >> si) & 1;   // uniform across wave
            if (!keep_i) continue;
            float yi1 = __shfl(by1[si], oi), xi1 = __shfl(bx1[si], oi);
            float yi2 = __shfl(by2[si], oi), xi2 = __shfl(bx2[si], oi);
            float ai  = __shfl(bar[si], oi);
            #pragma unroll
            for (int s = 0; s < 4; ++s) {
                int jj = s * 64 + lane;
                if (jj > i && jj < L && ((kmask >> s) & 1)) {
                    float yy1 = fmaxf(yi1, by1[s]), xx1 = fmaxf(xi1, bx1[s]);
                    float yy2 = fminf(yi2, by2[s]), xx2 = fminf(xi2, bx2[s]);
                    float inter = fmaxf(yy2 - yy1, 0.f) * fmaxf(xx2 - xx1, 0.f);
                    float uni = ai + bar[s] - inter;
                    if (inter / (uni + EPSF) > IOU_TH) kmask &= ~(1 << s);
                }
            }
        }
        #pragma unroll
        for (int s = 0; s < 4; ++s) {
            int jj = s * 64 + lane;
            if (jj < L) skeep[jj] = (kmask >> s) & 1;
        }
    }
    __syncthreads();

    // one atomic per block, parallel prefix compaction
    if (threadIdx.x == 0) {
        int tot = 0;
        for (int i = 0; i < L; ++i) tot += skeep[i];
        sbase = atomicAdd(&final_count[b], tot);
    }
    __syncthreads();
    int base = sbase;

    for (int i = threadIdx.x; i < L; i += blockDim.x) {
        if (skeep[i]) {
            int pos = 0;
            for (int j = 0; j < i; ++j) pos += skeep[j];
            int slot = base + pos;
            if (slot < CAP) {
                Entry* fo = &fin[(size_t)b * CAP + slot];
                fo->s = ss[i]; fo->cls = c; fo->aux = i; fo->pad = 0;
                fo->y1 = sy1[i]; fo->x1 = sx1[i]; fo->y2 = sy2[i]; fo->x2 = sx2[i];
                sk[(size_t)b * CAP + slot].s = ss[i];
                sk[(size_t)b * CAP + slot].key = c * KK + i;
            }
        }
    }
}

// NCHUNK blocks per image: each thread ranks ONE entry against the LDS-resident
// list and writes its output row (ranks unique & dense -> no race). Chunk 0
// zeroes the tail [min(M,KK), KK) so no separate output-clear kernel is needed.
__global__ void k_topk(const int* __restrict__ final_count,
                       const Entry* __restrict__ fin,
                       const SK* __restrict__ sk,
                       float* __restrict__ out) {
    int b = blockIdx.x / NCHUNK, chunk = blockIdx.x % NCHUNK;
    int M = final_count[b];
    if (M > CAP) M = CAP;

    float* obox = out + (size_t)b * KK * 4;
    float* olbl = out + (size_t)NB * KK * 4 + (size_t)b * KK;
    float* osc  = out + (size_t)NB * KK * 5 + (size_t)b * KK;

    if (chunk == 0) {   // zero the unwritten tail every call (deterministic output)
        int Mi = M < KK ? M : KK;
        for (int i = Mi + (int)threadIdx.x; i < KK; i += blockDim.x) {
            obox[i * 4 + 0] = 0.f; obox[i * 4 + 1] = 0.f;
            obox[i * 4 + 2] = 0.f; obox[i * 4 + 3] = 0.f;
            olbl[i] = 0.f; osc[i] = 0.f;
        }
    }
    if (chunk * TCHUNK >= M) return;

    __shared__ float sS[CAP];
    __shared__ int   sKy[CAP];
    const SK* list = sk + (size_t)b * CAP;
    for (int i = threadIdx.x; i < M; i += blockDim.x) {
        SK v = list[i];
        sS[i] = v.s; sKy[i] = v.key;
    }
    __syncthreads();

    int e = chunk * TCHUNK + threadIdx.x;
    if (e >= M) return;
    float se = sS[e]; int ke = sKy[e];
    int rank = 0;
    for (int j = 0; j < M; ++j) {
        float sj = sS[j]; int kj = sKy[j];
        rank += (int)((sj > se) | ((sj == se) & (kj < ke)));
    }
    if (rank < KK) {
        Entry en = fin[(size_t)b * CAP + e];
        obox[rank * 4 + 0] = fminf(fmaxf(en.y1, 0.f), 1.f);
        obox[rank * 4 + 1] = fminf(fmaxf(en.x1, 0.f), 1.f);
        obox[rank * 4 + 2] = fminf(fmaxf(en.y2, 0.f), 1.f);
        obox[rank * 4 + 3] = fminf(fmaxf(en.x2, 0.f), 1.f);
        olbl[rank] = (float)en.cls;
        osc[rank]  = en.s;
    }
}

extern "C" void kernel_launch(void* const* d_in, const int* in_sizes, int n_in,
                              void* d_out, int out_size, void* d_ws, size_t ws_size,
                              hipStream_t stream) {
    const float* roi    = (const float*)d_in[0];
    const float* deltas = (const float*)d_in[1];
    const float* probs  = (const float*)d_in[2];
    float* out = (float*)d_out;

    int* ws_i        = (int*)d_ws;
    int* counts      = ws_i;                 // NB*NC ints
    int* final_count = ws_i + NB * NC;       // NB ints (contiguous with counts)
    Entry* cand = (Entry*)((char*)d_ws + 16384);              // NB*NC*SEGCAP*32B = 42.5MB
    Entry* fin  = cand + (size_t)NB * NC * SEGCAP;            // 2MB
    SK*    sk   = (SK*)(fin + (size_t)NB * CAP);              // 512KB

    hipMemsetAsync(counts, 0, (NB * NC + NB) * sizeof(int), stream);
    k_classify<<<GRID, 256, 0, stream>>>(roi, deltas, probs, counts, cand);
    k_perclass<<<NB * NC, 256, 0, stream>>>(counts, cand, final_count, fin, sk);
    k_topk<<<NB * NCHUNK, 256, 0, stream>>>(final_count, fin, sk, out);
}

// Round 8
// 91.098 us; speedup vs baseline: 3.7382x; 1.0012x over previous
//
#include <hip/hip_runtime.h>
#include <math.h>

#pragma clang fp contract(off)

constexpr int NB  = 16;    // batch
constexpr int NR  = 4096;  // rois per image
constexpr int NC  = 81;    // classes (incl. background)
constexpr int KK  = 200;   // per-class candidate cap == max_total
constexpr int CAP = 4096;  // max kept entries per image
constexpr int SEGCAP = 1024;              // fixed-stride per-(b,c) candidate segment
constexpr int ROWS_PER_BLK = 64;
constexpr int GRID = NB * NR / ROWS_PER_BLK;  // 1024 blocks
constexpr int TCHUNK = 256;               // entries ranked per block in topk
constexpr int NCHUNK = CAP / TCHUNK;      // 16 blocks per image
constexpr float SCORE_TH = 0.5f;
constexpr float IOU_TH   = 0.5f;
constexpr float EPSF     = 1e-8f;

struct Entry {            // 32 bytes
    float s;
    int   cls;
    int   aux;            // roi index (cand) or pre-NMS rank k (final)
    int   pad;
    float y1, x1, y2, x2;
};
static_assert(sizeof(Entry) == 32, "Entry must be 32B");

struct SK { float s; int key; };   // 8B packed (score, cls*KK + prenms_rank)

__device__ __forceinline__ void decode_box(const float4& a, const float4& d,
                                           float& y1, float& x1, float& y2, float& x2) {
    float ah  = a.z - a.x;
    float aw  = a.w - a.y;
    float acy = a.x + 0.5f * ah;
    float acx = a.y + 0.5f * aw;
    float dy = d.x * 0.1f, dx = d.y * 0.1f;
    float dh = d.z * 0.2f, dw = d.w * 0.2f;
    float bh  = expf(dh) * ah;
    float bw  = expf(dw) * aw;
    float bcy = dy * ah + acy;
    float bcx = dx * aw + acx;
    y1 = bcy - 0.5f * bh;
    x1 = bcx - 0.5f * bw;
    y2 = y1 + bh;
    x2 = x1 + bw;
}

// zero counts[NB*NC] + final_count[NB]  (kernel, NOT hipMemsetAsync: a graph-
// captured 5KB fill node measured ~50us on this harness — kernel is ~3us)
__global__ void k_init(int* __restrict__ counts) {
    int i = blockIdx.x * blockDim.x + threadIdx.x;
    if (i < NB * NC + NB) counts[i] = 0;
}

// 4 threads per ROI: LDS-staged coalesced probs, shfl argmax (first-max rule),
// leader decodes box and scatters into fixed-stride (b,c) segment.
__global__ void k_classify(const float* __restrict__ roi,
                           const float* __restrict__ deltas,
                           const float* __restrict__ probs,
                           int* __restrict__ counts,
                           Entry* __restrict__ cand) {
    __shared__ float lp[ROWS_PER_BLK * NC];   // 20736 B
    const float4* src = (const float4*)(probs + (size_t)blockIdx.x * ROWS_PER_BLK * NC);
    float4* dst = (float4*)lp;
    for (int v = threadIdx.x; v < ROWS_PER_BLK * NC / 4; v += blockDim.x) dst[v] = src[v];
    __syncthreads();

    int g = threadIdx.x >> 2;       // row within block
    int j = threadIdx.x & 3;        // sub-lane within row group
    const float* row = lp + g * NC;
    float m = -1.0f;
    int am = 127;
    for (int c = j; c < NC; c += 4) {
        float v = row[c];
        if (v > m) { m = v; am = c; }            // first-max within subset
    }
    for (int mask = 1; mask <= 2; mask <<= 1) {  // tie -> smaller index (jnp.argmax)
        float om = __shfl_xor(m, mask);
        int   oi = __shfl_xor(am, mask);
        if (om > m || (om == m && oi < am)) { m = om; am = oi; }
    }
    if (j != 0) return;
    if (am == 0 || !(m > SCORE_TH)) return;      // background or below threshold

    int r = blockIdx.x * ROWS_PER_BLK + g;
    int b = r / NR;
    float4 a = ((const float4*)roi)[r];
    float4 d = *(const float4*)(deltas + ((size_t)r * NC + am) * 4);
    float y1, x1, y2, x2;
    decode_box(a, d, y1, x1, y2, x2);
    int slot = atomicAdd(&counts[b * NC + am], 1);
    if (slot < SEGCAP) {
        Entry* e = &cand[(size_t)(b * NC + am) * SEGCAP + slot];
        e->s = m; e->cls = am; e->aux = r % NR; e->pad = 0;
        e->y1 = y1; e->x1 = x1; e->y2 = y2; e->x2 = x2;
    }
}

// One block per (image,class): LDS rank -> top-200 -> wave-synchronous greedy NMS
// (wave 0, no barriers in the i-loop) -> aggregated append.
__global__ void k_perclass(const int* __restrict__ counts,
                           const Entry* __restrict__ cand,
                           int* __restrict__ final_count,
                           Entry* __restrict__ fin,
                           SK* __restrict__ sk) {
    int b = blockIdx.x / NC, c = blockIdx.x % NC;
    if (c == 0) return;
    int Mc = counts[b * NC + c];
    if (Mc > SEGCAP) Mc = SEGCAP;
    if (Mc == 0) return;
    const Entry* seg = cand + (size_t)(b * NC + c) * SEGCAP;

    __shared__ float ls[SEGCAP], ly1[SEGCAP], lx1[SEGCAP], ly2[SEGCAP], lx2[SEGCAP];
    __shared__ int   lroi[SEGCAP];
    __shared__ float ss[KK], sy1[KK], sx1[KK], sy2[KK], sx2[KK], sar[KK];
    __shared__ int   skeep[KK];
    __shared__ int   sbase;

    for (int i = threadIdx.x; i < Mc; i += blockDim.x) {
        Entry e = seg[i];
        ls[i] = e.s; lroi[i] = e.aux;
        ly1[i] = e.y1; lx1[i] = e.x1; ly2[i] = e.y2; lx2[i] = e.x2;
    }
    __syncthreads();

    // stable rank by (score desc, roi asc) — lax.top_k order
    for (int i = threadIdx.x; i < Mc; i += blockDim.x) {
        float si = ls[i]; int ri = lroi[i];
        int rank = 0;
        for (int j = 0; j < Mc; ++j) {
            float sj = ls[j]; int rj = lroi[j];
            rank += (int)((sj > si) | ((sj == si) & (rj < ri)));
        }
        if (rank < KK) {
            ss[rank] = si;
            sy1[rank] = ly1[i]; sx1[rank] = lx1[i];
            sy2[rank] = ly2[i]; sx2[rank] = lx2[i];
            sar[rank] = fmaxf(ly2[i] - ly1[i], 0.f) * fmaxf(lx2[i] - lx1[i], 0.f);
        }
    }
    __syncthreads();

    int L = Mc < KK ? Mc : KK;

    // ---- wave-synchronous greedy NMS on wave 0 (items j owned by lane j&63,
    //      slot j>>6; keep bits in a per-lane register mask; no barriers) ----
    if (threadIdx.x < 64) {
        int lane = threadIdx.x;
        float by1[4], bx1[4], by2[4], bx2[4], bar[4];
        #pragma unroll
        for (int s = 0; s < 4; ++s) {
            int jj = s * 64 + lane;
            if (jj < L) { by1[s] = sy1[jj]; bx1[s] = sx1[jj]; by2[s] = sy2[jj];
                          bx2[s] = sx2[jj]; bar[s] = sar[jj]; }
        }
        int kmask = 0;
        #pragma unroll
        for (int s = 0; s < 4; ++s) if (s * 64 + lane < L) kmask |= 1 << s;

        for (int i = 0; i < L; ++i) {
            int oi = i & 63, si = i >> 6;                 // owner lane, slot (uniform si)
            int keep_i = (__shfl(kmask, oi) >> si) & 1;   // uniform across wave
            if (!keep_i) continue;
            float yi1 = __shfl(by1[si], oi), xi1 = __shfl(bx1[si], oi);
            float yi2 = __shfl(by2[si], oi), xi2 = __shfl(bx2[si], oi);
            float ai  = __shfl(bar[si], oi);
            #pragma unroll
            for (int s = 0; s < 4; ++s) {
                int jj = s * 64 + lane;
                if (jj > i && jj < L && ((kmask >> s) & 1)) {
                    float yy1 = fmaxf(yi1, by1[s]), xx1 = fmaxf(xi1, bx1[s]);
                    float yy2 = fminf(yi2, by2[s]), xx2 = fminf(xi2, bx2[s]);
                    float inter = fmaxf(yy2 - yy1, 0.f) * fmaxf(xx2 - xx1, 0.f);
                    float uni = ai + bar[s] - inter;
                    if (inter / (uni + EPSF) > IOU_TH) kmask &= ~(1 << s);
                }
            }
        }
        #pragma unroll
        for (int s = 0; s < 4; ++s) {
            int jj = s * 64 + lane;
            if (jj < L) skeep[jj] = (kmask >> s) & 1;
        }
    }
    __syncthreads();

    // one atomic per block, parallel prefix compaction
    if (threadIdx.x == 0) {
        int tot = 0;
        for (int i = 0; i < L; ++i) tot += skeep[i];
        sbase = atomicAdd(&final_count[b], tot);
    }
    __syncthreads();
    int base = sbase;

    for (int i = threadIdx.x; i < L; i += blockDim.x) {
        if (skeep[i]) {
            int pos = 0;
            for (int j = 0; j < i; ++j) pos += skeep[j];
            int slot = base + pos;
            if (slot < CAP) {
                Entry* fo = &fin[(size_t)b * CAP + slot];
                fo->s = ss[i]; fo->cls = c; fo->aux = i; fo->pad = 0;
                fo->y1 = sy1[i]; fo->x1 = sx1[i]; fo->y2 = sy2[i]; fo->x2 = sx2[i];
                sk[(size_t)b * CAP + slot].s = ss[i];
                sk[(size_t)b * CAP + slot].key = c * KK + i;
            }
        }
    }
}

// NCHUNK blocks per image: each thread ranks ONE entry against the LDS-resident
// list and writes its output row (ranks unique & dense -> no race). Chunk 0
// zeroes the tail [min(M,KK), KK) so no separate output-clear pass is needed.
__global__ void k_topk(const int* __restrict__ final_count,
                       const Entry* __restrict__ fin,
                       const SK* __restrict__ sk,
                       float* __restrict__ out) {
    int b = blockIdx.x / NCHUNK, chunk = blockIdx.x % NCHUNK;
    int M = final_count[b];
    if (M > CAP) M = CAP;

    float* obox = out + (size_t)b * KK * 4;
    float* olbl = out + (size_t)NB * KK * 4 + (size_t)b * KK;
    float* osc  = out + (size_t)NB * KK * 5 + (size_t)b * KK;

    if (chunk == 0) {   // zero the unwritten tail every call (deterministic output)
        int Mi = M < KK ? M : KK;
        for (int i = Mi + (int)threadIdx.x; i < KK; i += blockDim.x) {
            obox[i * 4 + 0] = 0.f; obox[i * 4 + 1] = 0.f;
            obox[i * 4 + 2] = 0.f; obox[i * 4 + 3] = 0.f;
            olbl[i] = 0.f; osc[i] = 0.f;
        }
    }
    if (chunk * TCHUNK >= M) return;

    __shared__ float sS[CAP];
    __shared__ int   sKy[CAP];
    const SK* list = sk + (size_t)b * CAP;
    for (int i = threadIdx.x; i < M; i += blockDim.x) {
        SK v = list[i];
        sS[i] = v.s; sKy[i] = v.key;
    }
    __syncthreads();

    int e = chunk * TCHUNK + threadIdx.x;
    if (e >= M) return;
    float se = sS[e]; int ke = sKy[e];
    int rank = 0;
    for (int j = 0; j < M; ++j) {
        float sj = sS[j]; int kj = sKy[j];
        rank += (int)((sj > se) | ((sj == se) & (kj < ke)));
    }
    if (rank < KK) {
        Entry en = fin[(size_t)b * CAP + e];
        obox[rank * 4 + 0] = fminf(fmaxf(en.y1, 0.f), 1.f);
        obox[rank * 4 + 1] = fminf(fmaxf(en.x1, 0.f), 1.f);
        obox[rank * 4 + 2] = fminf(fmaxf(en.y2, 0.f), 1.f);
        obox[rank * 4 + 3] = fminf(fmaxf(en.x2, 0.f), 1.f);
        olbl[rank] = (float)en.cls;
        osc[rank]  = en.s;
    }
}

extern "C" void kernel_launch(void* const* d_in, const int* in_sizes, int n_in,
                              void* d_out, int out_size, void* d_ws, size_t ws_size,
                              hipStream_t stream) {
    const float* roi    = (const float*)d_in[0];
    const float* deltas = (const float*)d_in[1];
    const float* probs  = (const float*)d_in[2];
    float* out = (float*)d_out;

    int* ws_i        = (int*)d_ws;
    int* counts      = ws_i;                 // NB*NC ints
    int* final_count = ws_i + NB * NC;       // NB ints (contiguous with counts)
    Entry* cand = (Entry*)((char*)d_ws + 16384);              // NB*NC*SEGCAP*32B = 42.5MB
    Entry* fin  = cand + (size_t)NB * NC * SEGCAP;            // 2MB
    SK*    sk   = (SK*)(fin + (size_t)NB * CAP);              // 512KB

    k_init<<<(NB * NC + NB + 255) / 256, 256, 0, stream>>>(counts);
    k_classify<<<GRID, 256, 0, stream>>>(roi, deltas, probs, counts, cand);
    k_perclass<<<NB * NC, 256, 0, stream>>>(counts, cand, final_count, fin, sk);
    k_topk<<<NB * NCHUNK, 256, 0, stream>>>(final_count, fin, sk, out);
}

// Round 9
// 80.502 us; speedup vs baseline: 4.2303x; 1.1316x over previous
//
#include <hip/hip_runtime.h>
#include <math.h>

#pragma clang fp contract(off)

constexpr int NB  = 16;    // batch
constexpr int NR  = 4096;  // rois per image
constexpr int NC  = 81;    // classes (incl. background)
constexpr int KK  = 200;   // per-class candidate cap == max_total
constexpr int CAP = 4096;  // max kept entries per image
constexpr int SEGCAP = 1024;              // fixed-stride per-(b,c) candidate segment
constexpr int ROWS_PER_BLK = 64;
constexpr int GRID = NB * NR / ROWS_PER_BLK;  // 1024 blocks
constexpr int TCHUNK = 256;               // entries ranked per block in topk
constexpr int NCHUNK = CAP / TCHUNK;      // 16 blocks per image
constexpr float SCORE_TH = 0.5f;
constexpr float IOU_TH   = 0.5f;
constexpr float EPSF     = 1e-8f;

struct Entry {            // 32 bytes
    float s;
    int   cls;
    int   aux;            // roi index (cand) or pre-NMS rank k (final)
    int   pad;
    float y1, x1, y2, x2;
};
static_assert(sizeof(Entry) == 32, "Entry must be 32B");

struct SK { float s; int key; };   // 8B packed (score, cls*KK + prenms_rank)

__device__ __forceinline__ void decode_box(const float4& a, const float4& d,
                                           float& y1, float& x1, float& y2, float& x2) {
    float ah  = a.z - a.x;
    float aw  = a.w - a.y;
    float acy = a.x + 0.5f * ah;
    float acx = a.y + 0.5f * aw;
    float dy = d.x * 0.1f, dx = d.y * 0.1f;
    float dh = d.z * 0.2f, dw = d.w * 0.2f;
    float bh  = expf(dh) * ah;
    float bw  = expf(dw) * aw;
    float bcy = dy * ah + acy;
    float bcx = dx * aw + acx;
    y1 = bcy - 0.5f * bh;
    x1 = bcx - 0.5f * bw;
    y2 = y1 + bh;
    x2 = x1 + bw;
}

// zero counts[NB*NC] + final_count[NB]
__global__ void k_init(int* __restrict__ counts) {
    int i = blockIdx.x * blockDim.x + threadIdx.x;
    if (i < NB * NC + NB) counts[i] = 0;
}

// 4 threads per ROI: LDS-staged coalesced probs, shfl argmax (first-max rule),
// leader decodes box and scatters into fixed-stride (b,c) segment.
__global__ void k_classify(const float* __restrict__ roi,
                           const float* __restrict__ deltas,
                           const float* __restrict__ probs,
                           int* __restrict__ counts,
                           Entry* __restrict__ cand) {
    __shared__ float lp[ROWS_PER_BLK * NC];   // 20736 B
    const float4* src = (const float4*)(probs + (size_t)blockIdx.x * ROWS_PER_BLK * NC);
    float4* dst = (float4*)lp;
    for (int v = threadIdx.x; v < ROWS_PER_BLK * NC / 4; v += blockDim.x) dst[v] = src[v];
    __syncthreads();

    int g = threadIdx.x >> 2;       // row within block
    int j = threadIdx.x & 3;        // sub-lane within row group
    const float* row = lp + g * NC;
    float m = -1.0f;
    int am = 127;
    for (int c = j; c < NC; c += 4) {
        float v = row[c];
        if (v > m) { m = v; am = c; }            // first-max within subset
    }
    for (int mask = 1; mask <= 2; mask <<= 1) {  // tie -> smaller index (jnp.argmax)
        float om = __shfl_xor(m, mask);
        int   oi = __shfl_xor(am, mask);
        if (om > m || (om == m && oi < am)) { m = om; am = oi; }
    }
    if (j != 0) return;
    if (am == 0 || !(m > SCORE_TH)) return;      // background or below threshold

    int r = blockIdx.x * ROWS_PER_BLK + g;
    int b = r / NR;
    float4 a = ((const float4*)roi)[r];
    float4 d = *(const float4*)(deltas + ((size_t)r * NC + am) * 4);
    float y1, x1, y2, x2;
    decode_box(a, d, y1, x1, y2, x2);
    int slot = atomicAdd(&counts[b * NC + am], 1);
    if (slot < SEGCAP) {
        Entry* e = &cand[(size_t)(b * NC + am) * SEGCAP + slot];
        e->s = m; e->cls = am; e->aux = r % NR; e->pad = 0;
        e->y1 = y1; e->x1 = x1; e->y2 = y2; e->x2 = x2;
    }
}

// One block per (image,class): LDS rank -> top-200 -> mask-NMS -> append.
// NMS = (a) parallel build of 256-bit suppression masks sup[i] = {j>i: iou>TH}
//       (all 256 threads, no dependencies), then (b) greedy scan on wave 0
//       with keep-bits in registers (4 bits/lane) — short dependent chain.
__global__ void k_perclass(const int* __restrict__ counts,
                           const Entry* __restrict__ cand,
                           int* __restrict__ final_count,
                           Entry* __restrict__ fin,
                           SK* __restrict__ sk) {
    int b = blockIdx.x / NC, c = blockIdx.x % NC;
    if (c == 0) return;
    int Mc = counts[b * NC + c];
    if (Mc > SEGCAP) Mc = SEGCAP;
    if (Mc == 0) return;
    const Entry* seg = cand + (size_t)(b * NC + c) * SEGCAP;

    __shared__ float ls[SEGCAP], ly1[SEGCAP], lx1[SEGCAP], ly2[SEGCAP], lx2[SEGCAP];
    __shared__ int   lroi[SEGCAP];
    __shared__ float ss[KK], sy1[KK], sx1[KK], sy2[KK], sx2[KK], sar[KK];
    __shared__ unsigned long long sup[KK][4];   // 6.4 KB suppression masks
    __shared__ int   skeep[KK];
    __shared__ int   sbase;

    for (int i = threadIdx.x; i < Mc; i += blockDim.x) {
        Entry e = seg[i];
        ls[i] = e.s; lroi[i] = e.aux;
        ly1[i] = e.y1; lx1[i] = e.x1; ly2[i] = e.y2; lx2[i] = e.x2;
    }
    __syncthreads();

    // stable rank by (score desc, roi asc) — lax.top_k order
    for (int i = threadIdx.x; i < Mc; i += blockDim.x) {
        float si = ls[i]; int ri = lroi[i];
        int rank = 0;
        for (int j = 0; j < Mc; ++j) {
            float sj = ls[j]; int rj = lroi[j];
            rank += (int)((sj > si) | ((sj == si) & (rj < ri)));
        }
        if (rank < KK) {
            ss[rank] = si;
            sy1[rank] = ly1[i]; sx1[rank] = lx1[i];
            sy2[rank] = ly2[i]; sx2[rank] = lx2[i];
            sar[rank] = fmaxf(ly2[i] - ly1[i], 0.f) * fmaxf(lx2[i] - lx1[i], 0.f);
        }
    }
    __syncthreads();

    int L = Mc < KK ? Mc : KK;

    // (a) build suppression masks — fully parallel, no atomics
    for (int idx = threadIdx.x; idx < L * 4; idx += blockDim.x) {
        int i = idx >> 2, w = idx & 3;
        int j0 = w * 64;
        unsigned long long bits = 0;
        int jend = j0 + 64 < L ? j0 + 64 : L;
        int jstart = j0 > i + 1 ? j0 : i + 1;
        if (jstart < jend) {
            float yi1 = sy1[i], xi1 = sx1[i], yi2 = sy2[i], xi2 = sx2[i], ai = sar[i];
            for (int j = jstart; j < jend; ++j) {
                float yy1 = fmaxf(yi1, sy1[j]), xx1 = fmaxf(xi1, sx1[j]);
                float yy2 = fminf(yi2, sy2[j]), xx2 = fminf(xi2, sx2[j]);
                float inter = fmaxf(yy2 - yy1, 0.f) * fmaxf(xx2 - xx1, 0.f);
                float uni = ai + sar[j] - inter;
                if (inter / (uni + EPSF) > IOU_TH) bits |= 1ull << (j - j0);
            }
        }
        sup[i][w] = bits;
    }
    __syncthreads();

    // (b) greedy scan, wave 0: lane l keeps bits for items s*64+l (s=0..3)
    if (threadIdx.x < 64) {
        int lane = threadIdx.x;
        int kmask = 0;
        #pragma unroll
        for (int s = 0; s < 4; ++s) if (s * 64 + lane < L) kmask |= 1 << s;

        for (int i = 0; i < L; ++i) {
            int oi = i & 63, si = i >> 6;
            unsigned long long r0 = sup[i][0], r1 = sup[i][1];
            unsigned long long r2 = sup[i][2], r3 = sup[i][3];
            int keep_i = (__shfl(kmask, oi) >> si) & 1;   // uniform across wave
            if (keep_i) {
                int supb = (int)((r0 >> lane) & 1)
                         | ((int)((r1 >> lane) & 1) << 1)
                         | ((int)((r2 >> lane) & 1) << 2)
                         | ((int)((r3 >> lane) & 1) << 3);
                kmask &= ~supb;
            }
        }
        #pragma unroll
        for (int s = 0; s < 4; ++s) {
            int jj = s * 64 + lane;
            if (jj < L) skeep[jj] = (kmask >> s) & 1;
        }
    }
    __syncthreads();

    // one atomic per block, parallel prefix compaction
    if (threadIdx.x == 0) {
        int tot = 0;
        for (int i = 0; i < L; ++i) tot += skeep[i];
        sbase = atomicAdd(&final_count[b], tot);
    }
    __syncthreads();
    int base = sbase;

    for (int i = threadIdx.x; i < L; i += blockDim.x) {
        if (skeep[i]) {
            int pos = 0;
            for (int j = 0; j < i; ++j) pos += skeep[j];
            int slot = base + pos;
            if (slot < CAP) {
                Entry* fo = &fin[(size_t)b * CAP + slot];
                fo->s = ss[i]; fo->cls = c; fo->aux = i; fo->pad = 0;
                fo->y1 = sy1[i]; fo->x1 = sx1[i]; fo->y2 = sy2[i]; fo->x2 = sx2[i];
                sk[(size_t)b * CAP + slot].s = ss[i];
                sk[(size_t)b * CAP + slot].key = c * KK + i;
            }
        }
    }
}

// NCHUNK blocks per image: thread ranks ONE entry against the LDS-resident
// packed list (ds_read_b128 = 2 entries/instr). Ranks unique & dense -> no race.
__global__ void k_topk(const int* __restrict__ final_count,
                       const Entry* __restrict__ fin,
                       const SK* __restrict__ sk,
                       float* __restrict__ out) {
    int b = blockIdx.x / NCHUNK, chunk = blockIdx.x % NCHUNK;
    int M = final_count[b];
    if (M > CAP) M = CAP;

    float* obox = out + (size_t)b * KK * 4;
    float* olbl = out + (size_t)NB * KK * 4 + (size_t)b * KK;
    float* osc  = out + (size_t)NB * KK * 5 + (size_t)b * KK;

    if (chunk == 0) {   // zero the unwritten tail every call (deterministic output)
        int Mi = M < KK ? M : KK;
        for (int i = Mi + (int)threadIdx.x; i < KK; i += blockDim.x) {
            obox[i * 4 + 0] = 0.f; obox[i * 4 + 1] = 0.f;
            obox[i * 4 + 2] = 0.f; obox[i * 4 + 3] = 0.f;
            olbl[i] = 0.f; osc[i] = 0.f;
        }
    }
    if (chunk * TCHUNK >= M) return;

    __shared__ SK sL[CAP];   // 32 KB packed (score,key)
    const float2* src = (const float2*)(sk + (size_t)b * CAP);
    float2* dstv = (float2*)sL;
    for (int i = threadIdx.x; i < M; i += blockDim.x) dstv[i] = src[i];
    __syncthreads();

    int e = chunk * TCHUNK + threadIdx.x;
    if (e >= M) return;
    float se = sL[e].s; int ke = sL[e].key;
    int rank = 0;
    const float4* p4 = (const float4*)sL;   // 2 SK per float4
    int npair = M >> 1;
    #pragma unroll 4
    for (int p = 0; p < npair; ++p) {
        float4 v = p4[p];
        int k0 = __float_as_int(v.y), k1 = __float_as_int(v.w);
        rank += (int)((v.x > se) | ((v.x == se) & (k0 < ke)));
        rank += (int)((v.z > se) | ((v.z == se) & (k1 < ke)));
    }
    if (M & 1) {
        float sj = sL[M - 1].s; int kj = sL[M - 1].key;
        rank += (int)((sj > se) | ((sj == se) & (kj < ke)));
    }
    if (rank < KK) {
        Entry en = fin[(size_t)b * CAP + e];
        obox[rank * 4 + 0] = fminf(fmaxf(en.y1, 0.f), 1.f);
        obox[rank * 4 + 1] = fminf(fmaxf(en.x1, 0.f), 1.f);
        obox[rank * 4 + 2] = fminf(fmaxf(en.y2, 0.f), 1.f);
        obox[rank * 4 + 3] = fminf(fmaxf(en.x2, 0.f), 1.f);
        olbl[rank] = (float)en.cls;
        osc[rank]  = en.s;
    }
}

extern "C" void kernel_launch(void* const* d_in, const int* in_sizes, int n_in,
                              void* d_out, int out_size, void* d_ws, size_t ws_size,
                              hipStream_t stream) {
    const float* roi    = (const float*)d_in[0];
    const float* deltas = (const float*)d_in[1];
    const float* probs  = (const float*)d_in[2];
    float* out = (float*)d_out;

    int* ws_i        = (int*)d_ws;
    int* counts      = ws_i;                 // NB*NC ints
    int* final_count = ws_i + NB * NC;       // NB ints (contiguous with counts)
    Entry* cand = (Entry*)((char*)d_ws + 16384);              // NB*NC*SEGCAP*32B = 42.5MB
    Entry* fin  = cand + (size_t)NB * NC * SEGCAP;            // 2MB
    SK*    sk   = (SK*)(fin + (size_t)NB * CAP);              // 512KB

    k_init<<<(NB * NC + NB + 255) / 256, 256, 0, stream>>>(counts);
    k_classify<<<GRID, 256, 0, stream>>>(roi, deltas, probs, counts, cand);
    k_perclass<<<NB * NC, 256, 0, stream>>>(counts, cand, final_count, fin, sk);
    k_topk<<<NB * NCHUNK, 256, 0, stream>>>(final_count, fin, sk, out);
}